// Round 7
// baseline (758.459 us; speedup 1.0000x reference)
//
#include <hip/hip_runtime.h>
#include <hip/hip_bf16.h>

// Shapes: B=128, T=16, L=32, D=256, H=8, E=V=64. TL = T*L = 512.
// d_out layout (floats): [0, 4194304) attn_output (B,T,L,64)
//                        [4194304, 71303168) scores (T,L,H,128,128)
//  - K0 parks Wt (bf16, [3][512][256]) at the start of the attn region.
//  - K1 packs per-(t,l,h) slot (64 KB): Q[b=128][e=64] | K[b=128][e=64] |
//    V^T[e=64][b=128] (bf16, 48 KB used); K2 reads them then overwrites the
//    slot with fp32 scores. No d_ws usage.
//  - K1 R7: occupancy play. 512 thr (8 waves), wave = head, acc[4][4] over
//    two bh passes, kk loop unroll 1 to keep VGPR <= 128 so 2 blocks/CU
//    co-reside -> 16 waves/CU (2x R2, 2.5x R6). Staging latency hides
//    under co-resident waves instead of stalling the whole CU.

using bf16x8 = __attribute__((ext_vector_type(8))) __bf16;
using bf16x4 = __attribute__((ext_vector_type(4))) __bf16;
using f32x4  = __attribute__((ext_vector_type(4))) float;

__device__ __forceinline__ f32x4 mfma16(bf16x8 a, bf16x8 b, f32x4 c) {
  return __builtin_amdgcn_mfma_f32_16x16x32_bf16(a, b, c, 0, 0, 0);
}

// ---------------- K0: W (256,8,64) fp32 -> Wt[mat][col=512][d=256] bf16 ----
__global__ __launch_bounds__(512) void k0_wt(const float* __restrict__ Wq,
                                             const float* __restrict__ Wk,
                                             const float* __restrict__ Wv,
                                             __bf16* __restrict__ Wt) {
  int f   = blockIdx.x * 512 + threadIdx.x;   // 96*512 = 49152 threads
  int mat = f >> 14;
  int rem = f & 16383;
  int d8  = rem >> 9;          // 0..31  (octet of d)
  int col = rem & 511;         // 0..511 (h*64+e)
  const float* W = (mat == 0) ? Wq : (mat == 1) ? Wk : Wv;
  bf16x8 v;
#pragma unroll
  for (int i = 0; i < 8; ++i) v[i] = (__bf16)W[(d8 * 8 + i) * 512 + col];
  *(bf16x8*)(Wt + mat * 131072 + col * 256 + d8 * 8) = v;
}

// ---------------- K1: projections -----------------------------------------
// block = (tl, m), 512 thr. LDS: x[128][256] bf16 swz = 64 KB.
// Wave w = head w. Two bh passes of acc[4][4]; kk loop NOT unrolled.
__global__ __launch_bounds__(512, 4) void k1_proj(const float* __restrict__ xq,
                                                  const float* __restrict__ xk,
                                                  const float* __restrict__ xv,
                                                  const __bf16* __restrict__ Wt,
                                                  __bf16* __restrict__ qkv) {
  __shared__ char smem[65536];
  const int tid  = threadIdx.x;
  const int tl   = blockIdx.x;
  const int m    = blockIdx.y;
  const int lane = tid & 63, w = tid >> 6;
  const int lrow = lane & 15, lk = lane >> 4;
  const f32x4 z4 = {0.f, 0.f, 0.f, 0.f};

  const float* xm = (m == 0) ? xq : (m == 1) ? xk : xv;

  // stage x slice [b=128][d=256] -> bf16, XOR-swizzled rows of 512 B
#pragma unroll
  for (int i = 0; i < 8; ++i) {
    int c = i * 512 + tid;
    int row = c >> 5, sl = c & 31;
    const float* g = xm + (size_t)row * 131072 + (size_t)tl * 256 + sl * 8;
    float4 f0 = *(const float4*)g;
    float4 f1 = *(const float4*)(g + 4);
    bf16x8 v;
    v[0] = (__bf16)f0.x; v[1] = (__bf16)f0.y; v[2] = (__bf16)f0.z; v[3] = (__bf16)f0.w;
    v[4] = (__bf16)f1.x; v[5] = (__bf16)f1.y; v[6] = (__bf16)f1.z; v[7] = (__bf16)f1.w;
    *(bf16x8*)(smem + row * 512 + ((sl ^ (row & 7)) << 4)) = v;
  }
  __syncthreads();

  const int h = w;                                  // wave <-> head
  const __bf16* wbase = Wt + (size_t)(m * 512 + h * 64) * 256;
  __bf16* dst = qkv + (size_t)(tl * 8 + h) * 32768 + m * 8192;

#pragma unroll 1
  for (int bh = 0; bh < 2; ++bh) {                  // 64 b-rows per pass
    f32x4 acc[4][4];
#pragma unroll
    for (int bi = 0; bi < 4; ++bi)
#pragma unroll
      for (int ci = 0; ci < 4; ++ci) acc[bi][ci] = z4;

#pragma unroll 1
    for (int kk = 0; kk < 8; ++kk) {                // 8 LDS+L2 loads -> 16 MFMA
      bf16x8 wf[4], xf[4];
#pragma unroll
      for (int ci = 0; ci < 4; ++ci)
        wf[ci] = *(const bf16x8*)(wbase + (ci * 16 + lrow) * 256 + kk * 32 + lk * 8);
#pragma unroll
      for (int bi = 0; bi < 4; ++bi) {
        int row = bh * 64 + bi * 16 + lrow;
        xf[bi] = *(const bf16x8*)(smem + row * 512 +
                                  ((kk * 64 + lk * 16) ^ ((row & 7) << 4)));
      }
      if (m < 2) {                                  // D[e][b] = W^T x^T
#pragma unroll
        for (int bi = 0; bi < 4; ++bi)
#pragma unroll
          for (int ci = 0; ci < 4; ++ci)
            acc[bi][ci] = mfma16(wf[ci], xf[bi], acc[bi][ci]);
      } else {                                      // D[b][e] = x W
#pragma unroll
        for (int bi = 0; bi < 4; ++bi)
#pragma unroll
          for (int ci = 0; ci < 4; ++ci)
            acc[bi][ci] = mfma16(xf[bi], wf[ci], acc[bi][ci]);
      }
    }

    if (m < 2) {  // lane: e = ci*16+lk*4+r (consec), b = bh*64+bi*16+lrow
#pragma unroll
      for (int bi = 0; bi < 4; ++bi)
#pragma unroll
        for (int ci = 0; ci < 4; ++ci) {
          bf16x4 v;
#pragma unroll
          for (int r = 0; r < 4; ++r) v[r] = (__bf16)acc[bi][ci][r];
          int b = bh * 64 + bi * 16 + lrow;
          *(bf16x4*)(dst + b * 64 + ci * 16 + lk * 4) = v;      // [b][e]
        }
    } else {      // lane: b = bh*64+bi*16+lk*4+r (consec), e = ci*16+lrow
#pragma unroll
      for (int bi = 0; bi < 4; ++bi)
#pragma unroll
        for (int ci = 0; ci < 4; ++ci) {
          bf16x4 v;
#pragma unroll
          for (int r = 0; r < 4; ++r) v[r] = (__bf16)acc[bi][ci][r];
          int e = ci * 16 + lrow;
          *(bf16x4*)(dst + e * 128 + bh * 64 + bi * 16 + lk * 4) = v; // [e][b]
        }
    }
  }
}

// ---------------- K2: scores + softmax + PV + head mix --------------------
// block = (t,l), loops h. LDS: K 16K @0 | V^T 16K @16384 | P 32K @32768
__global__ __launch_bounds__(512) void k2_attn(const float* __restrict__ mask,
                                               const float* __restrict__ w_head,
                                               float* out_base) {
  __shared__ char smem[65536];
  const int tid  = threadIdx.x;
  const int tl   = blockIdx.x;
  const int lane = tid & 63, w = tid >> 6;
  const int lrow = lane & 15, lk = lane >> 4;
  const f32x4 z4 = {0.f, 0.f, 0.f, 0.f};

  float* scores = out_base + 4194304;

  // per-lane mask values (reused for all 8 heads)
  float mreg[8][4];
#pragma unroll
  for (int ct = 0; ct < 8; ++ct)
#pragma unroll
    for (int r = 0; r < 4; ++r)
      mreg[ct][r] = mask[(w * 16 + lk * 4 + r) * 128 + ct * 16 + lrow];

  f32x4 oacc[4];
#pragma unroll
  for (int i = 0; i < 4; ++i) oacc[i] = z4;

  const int arow = w * 16 + lrow;

  for (int h = 0; h < 8; ++h) {
    const __bf16* slot = (const __bf16*)scores + (size_t)(tl * 8 + h) * 32768;
    float wh = w_head[h];

    // Q fragments straight from global [b][e] (no LDS dependency)
    bf16x8 a0 = *(const bf16x8*)(slot + arow * 64 + lk * 8);
    bf16x8 a1 = *(const bf16x8*)(slot + arow * 64 + 32 + lk * 8);

    __syncthreads();  // previous head's LDS reads done
#pragma unroll
    for (int i = 0; i < 2; ++i) {
      int cc = i * 512 + tid;
      int krow = cc >> 3, ks = cc & 7;             // K[b][e], 128B LDS rows
      uint4 kv = *(const uint4*)(slot + 8192 + krow * 64 + ks * 8);
      *(uint4*)(smem + krow * 128 + ((ks ^ (krow & 7)) << 4)) = kv;
      int e = cc >> 4, vs = cc & 15;               // V^T[e][b], 256B LDS rows
      uint4 vv = *(const uint4*)(slot + 16384 + e * 128 + vs * 8);
      *(uint4*)(smem + 16384 + e * 256 + ((vs ^ (e & 7)) << 4)) = vv;
    }
    __syncthreads();

    // S = Q K^T  (wave strip = 16 rows x 128 cols)
    f32x4 sacc[8];
#pragma unroll
    for (int ct = 0; ct < 8; ++ct) {
      int bcol = ct * 16 + lrow;
      const char* kb = smem + bcol * 128;
      int bswz = (bcol & 7) << 4;
      bf16x8 b0 = *(const bf16x8*)(kb + ((lk * 16 + 0) ^ bswz));
      bf16x8 b1 = *(const bf16x8*)(kb + ((lk * 16 + 64) ^ bswz));
      sacc[ct] = mfma16(a0, b0, z4);
      sacc[ct] = mfma16(a1, b1, sacc[ct]);
    }

    // scale * mask, emit scores
    float* srow = scores + (size_t)(tl * 8 + h) * 16384;
#pragma unroll
    for (int ct = 0; ct < 8; ++ct)
#pragma unroll
      for (int r = 0; r < 4; ++r) {
        float s = sacc[ct][r] * 0.125f * mreg[ct][r];
        sacc[ct][r] = s;
        srow[(w * 16 + lk * 4 + r) * 128 + ct * 16 + lrow] = s;
      }

    // row softmax (row lives in one 16-lane group), fold w_head, P -> LDS
#pragma unroll
    for (int r = 0; r < 4; ++r) {
      float mx = sacc[0][r];
#pragma unroll
      for (int ct = 1; ct < 8; ++ct) mx = fmaxf(mx, sacc[ct][r]);
      mx = fmaxf(mx, __shfl_xor(mx, 1));
      mx = fmaxf(mx, __shfl_xor(mx, 2));
      mx = fmaxf(mx, __shfl_xor(mx, 4));
      mx = fmaxf(mx, __shfl_xor(mx, 8));
      float sum = 0.f;
#pragma unroll
      for (int ct = 0; ct < 8; ++ct) {
        float p = __expf(sacc[ct][r] - mx);
        sacc[ct][r] = p;
        sum += p;
      }
      sum += __shfl_xor(sum, 1);
      sum += __shfl_xor(sum, 2);
      sum += __shfl_xor(sum, 4);
      sum += __shfl_xor(sum, 8);
      float fct = wh / sum;
      int row16 = lk * 4 + r;
      char* pb = smem + 32768 + w * 4096 + row16 * 256;
      int pswz = (row16 & 7) << 4;
#pragma unroll
      for (int ct = 0; ct < 8; ++ct) {
        int col = ct * 16 + lrow;
        *(__bf16*)(pb + ((col * 2) ^ pswz)) = (__bf16)(sacc[ct][r] * fct);
      }
    }

    // PV: out_acc += (wh*P) @ V   (accumulates across heads)
    const char* pab = smem + 32768 + w * 4096 + lrow * 256;
    int paswz = (lrow & 7) << 4;
    bf16x8 pa[4];
#pragma unroll
    for (int kk = 0; kk < 4; ++kk)
      pa[kk] = *(const bf16x8*)(pab + ((lk * 16 + kk * 64) ^ paswz));
#pragma unroll
    for (int ct2 = 0; ct2 < 4; ++ct2) {
      int ecol = ct2 * 16 + lrow;
      const char* vb = smem + 16384 + ecol * 256;
      int vswz = (ecol & 7) << 4;
#pragma unroll
      for (int kk = 0; kk < 4; ++kk) {
        bf16x8 b = *(const bf16x8*)(vb + ((lk * 16 + kk * 64) ^ vswz));
        oacc[ct2] = mfma16(pa[kk], b, oacc[ct2]);
      }
    }
  }

  // attn_output[b,t,l,e] : (b*512 + tl)*64 + e
#pragma unroll
  for (int ct2 = 0; ct2 < 4; ++ct2)
#pragma unroll
    for (int r = 0; r < 4; ++r) {
      int brow = w * 16 + lk * 4 + r;
      int e    = ct2 * 16 + lrow;
      out_base[(size_t)(brow * 512 + tl) * 64 + e] = oacc[ct2][r];
    }
}

extern "C" void kernel_launch(void* const* d_in, const int* in_sizes, int n_in,
                              void* d_out, int out_size, void* d_ws, size_t ws_size,
                              hipStream_t stream) {
  const float* q    = (const float*)d_in[0];
  const float* k    = (const float*)d_in[1];
  const float* v    = (const float*)d_in[2];
  const float* mask = (const float*)d_in[3];
  const float* Wq   = (const float*)d_in[4];
  const float* Wk   = (const float*)d_in[5];
  const float* Wv   = (const float*)d_in[6];
  const float* wh   = (const float*)d_in[7];
  float* out = (float*)d_out;

  __bf16* Wt  = (__bf16*)out;                  // 786 KB, inside attn region
  __bf16* qkv = (__bf16*)(out + 4194304);      // packed into scores slots

  hipLaunchKernelGGL(k0_wt,   dim3(96),      dim3(512), 0, stream, Wq, Wk, Wv, Wt);
  hipLaunchKernelGGL(k1_proj, dim3(512, 3),  dim3(512), 0, stream, q, k, v, Wt, qkv);
  hipLaunchKernelGGL(k2_attn, dim3(512),     dim3(512), 0, stream, mask, wh, out);
}

// Round 8
// 383.972 us; speedup vs baseline: 1.9753x; 1.9753x over previous
//
#include <hip/hip_runtime.h>
#include <hip/hip_bf16.h>

// Shapes: B=128, T=16, L=32, D=256, H=8, E=V=64. TL = T*L = 512.
// d_out layout (floats): [0, 4194304) attn_output (B,T,L,64)
//                        [4194304, 71303168) scores (T,L,H,128,128)
//  - K0 parks Wt (bf16, [3][512][256]) at the start of the attn region.
//  - K1 packs per-(t,l,h) slot (64 KB): Q[b=128][e=64] | K[b=128][e=64] |
//    V^T[e=64][b=128] (bf16, 48 KB used); K2 reads them then overwrites the
//    slot with fp32 scores. No d_ws usage.
//  - K1 R8: 512 thr, wave = head, 4 passes of acc[2][4] (32b x 64e each).
//    Register budget ~90 VGPR (kk fully unrolled, branch hoisted) so
//    2 blocks/CU genuinely co-reside: staging of block n+1 overlaps
//    compute of block n. All qkv stores are full 64B-line bursts
//    (R5 showed 2.8x HBM write amplification from 32B partial lines).

using bf16x8 = __attribute__((ext_vector_type(8))) __bf16;
using bf16x4 = __attribute__((ext_vector_type(4))) __bf16;
using f32x4  = __attribute__((ext_vector_type(4))) float;

__device__ __forceinline__ f32x4 mfma16(bf16x8 a, bf16x8 b, f32x4 c) {
  return __builtin_amdgcn_mfma_f32_16x16x32_bf16(a, b, c, 0, 0, 0);
}

// ---------------- K0: W (256,8,64) fp32 -> Wt[mat][col=512][d=256] bf16 ----
__global__ __launch_bounds__(512) void k0_wt(const float* __restrict__ Wq,
                                             const float* __restrict__ Wk,
                                             const float* __restrict__ Wv,
                                             __bf16* __restrict__ Wt) {
  int f   = blockIdx.x * 512 + threadIdx.x;   // 96*512 = 49152 threads
  int mat = f >> 14;
  int rem = f & 16383;
  int d8  = rem >> 9;          // 0..31  (octet of d)
  int col = rem & 511;         // 0..511 (h*64+e)
  const float* W = (mat == 0) ? Wq : (mat == 1) ? Wk : Wv;
  bf16x8 v;
#pragma unroll
  for (int i = 0; i < 8; ++i) v[i] = (__bf16)W[(d8 * 8 + i) * 512 + col];
  *(bf16x8*)(Wt + mat * 131072 + col * 256 + d8 * 8) = v;
}

// ---------------- K1: projections -----------------------------------------
// block = (tl, m), 512 thr. LDS: x[128][256] bf16 swz = 64 KB.
__global__ __launch_bounds__(512, 4) void k1_proj(const float* __restrict__ xq,
                                                  const float* __restrict__ xk,
                                                  const float* __restrict__ xv,
                                                  const __bf16* __restrict__ Wt,
                                                  __bf16* __restrict__ qkv) {
  __shared__ char smem[65536];
  const int tid  = threadIdx.x;
  const int tl   = blockIdx.x;
  const int m    = blockIdx.y;
  const int lane = tid & 63, w = tid >> 6;
  const int lrow = lane & 15, lk = lane >> 4;
  const f32x4 z4 = {0.f, 0.f, 0.f, 0.f};

  const float* xm = (m == 0) ? xq : (m == 1) ? xk : xv;

  // stage x slice [b=128][d=256] -> bf16, XOR-swizzled rows of 512 B
#pragma unroll
  for (int i = 0; i < 8; ++i) {
    int c = i * 512 + tid;
    int row = c >> 5, sl = c & 31;
    const float* g = xm + (size_t)row * 131072 + (size_t)tl * 256 + sl * 8;
    float4 f0 = *(const float4*)g;
    float4 f1 = *(const float4*)(g + 4);
    bf16x8 v;
    v[0] = (__bf16)f0.x; v[1] = (__bf16)f0.y; v[2] = (__bf16)f0.z; v[3] = (__bf16)f0.w;
    v[4] = (__bf16)f1.x; v[5] = (__bf16)f1.y; v[6] = (__bf16)f1.z; v[7] = (__bf16)f1.w;
    *(bf16x8*)(smem + row * 512 + ((sl ^ (row & 7)) << 4)) = v;
  }
  __syncthreads();

  const int h = w;                                  // wave <-> head
  const __bf16* wbase = Wt + (size_t)(m * 512 + h * 64) * 256;
  __bf16* dst = qkv + (size_t)(tl * 8 + h) * 32768 + m * 8192;

  if (m < 2) {                                      // D[e][b] = W^T x^T
#pragma unroll 1
    for (int bq = 0; bq < 4; ++bq) {                // 32 b-rows per pass
      f32x4 acc[2][4];
#pragma unroll
      for (int bi = 0; bi < 2; ++bi)
#pragma unroll
        for (int ci = 0; ci < 4; ++ci) acc[bi][ci] = z4;
#pragma unroll
      for (int kk = 0; kk < 8; ++kk) {
        bf16x8 wf[4], xf[2];
#pragma unroll
        for (int ci = 0; ci < 4; ++ci)
          wf[ci] = *(const bf16x8*)(wbase + (ci * 16 + lrow) * 256 + kk * 32 + lk * 8);
#pragma unroll
        for (int bi = 0; bi < 2; ++bi) {
          int row = bq * 32 + bi * 16 + lrow;
          xf[bi] = *(const bf16x8*)(smem + row * 512 +
                                    ((kk * 64 + lk * 16) ^ ((row & 7) << 4)));
        }
#pragma unroll
        for (int bi = 0; bi < 2; ++bi)
#pragma unroll
          for (int ci = 0; ci < 4; ++ci)
            acc[bi][ci] = mfma16(wf[ci], xf[bi], acc[bi][ci]);
      }
      // store [b][e]: per row b, ci*16+lk*4 covers 0..63 e = 128B full lines
#pragma unroll
      for (int bi = 0; bi < 2; ++bi)
#pragma unroll
        for (int ci = 0; ci < 4; ++ci) {
          bf16x4 v;
#pragma unroll
          for (int r = 0; r < 4; ++r) v[r] = (__bf16)acc[bi][ci][r];
          int b = bq * 32 + bi * 16 + lrow;
          *(bf16x4*)(dst + b * 64 + ci * 16 + lk * 4) = v;
        }
    }
  } else {                                          // D[b][e] = x W
#pragma unroll 1
    for (int bq = 0; bq < 4; ++bq) {
      f32x4 acc[2][4];
#pragma unroll
      for (int bi = 0; bi < 2; ++bi)
#pragma unroll
        for (int ci = 0; ci < 4; ++ci) acc[bi][ci] = z4;
#pragma unroll
      for (int kk = 0; kk < 8; ++kk) {
        bf16x8 wf[4], xf[2];
#pragma unroll
        for (int ci = 0; ci < 4; ++ci)
          wf[ci] = *(const bf16x8*)(wbase + (ci * 16 + lrow) * 256 + kk * 32 + lk * 8);
#pragma unroll
        for (int bi = 0; bi < 2; ++bi) {
          int row = bq * 32 + bi * 16 + lrow;
          xf[bi] = *(const bf16x8*)(smem + row * 512 +
                                    ((kk * 64 + lk * 16) ^ ((row & 7) << 4)));
        }
#pragma unroll
        for (int bi = 0; bi < 2; ++bi)
#pragma unroll
          for (int ci = 0; ci < 4; ++ci)
            acc[bi][ci] = mfma16(xf[bi], wf[ci], acc[bi][ci]);
      }
      // store V^T [e][b]: per e-row, bq*32 + bi*16 + lk*4 covers 64B lines
#pragma unroll
      for (int bi = 0; bi < 2; ++bi)
#pragma unroll
        for (int ci = 0; ci < 4; ++ci) {
          bf16x4 v;
#pragma unroll
          for (int r = 0; r < 4; ++r) v[r] = (__bf16)acc[bi][ci][r];
          int e = ci * 16 + lrow;
          *(bf16x4*)(dst + e * 128 + bq * 32 + bi * 16 + lk * 4) = v;
        }
    }
  }
}

// ---------------- K2: scores + softmax + PV + head mix --------------------
// block = (t,l), loops h. LDS: K 16K @0 | V^T 16K @16384 | P 32K @32768
__global__ __launch_bounds__(512) void k2_attn(const float* __restrict__ mask,
                                               const float* __restrict__ w_head,
                                               float* out_base) {
  __shared__ char smem[65536];
  const int tid  = threadIdx.x;
  const int tl   = blockIdx.x;
  const int lane = tid & 63, w = tid >> 6;
  const int lrow = lane & 15, lk = lane >> 4;
  const f32x4 z4 = {0.f, 0.f, 0.f, 0.f};

  float* scores = out_base + 4194304;

  // per-lane mask values (reused for all 8 heads)
  float mreg[8][4];
#pragma unroll
  for (int ct = 0; ct < 8; ++ct)
#pragma unroll
    for (int r = 0; r < 4; ++r)
      mreg[ct][r] = mask[(w * 16 + lk * 4 + r) * 128 + ct * 16 + lrow];

  f32x4 oacc[4];
#pragma unroll
  for (int i = 0; i < 4; ++i) oacc[i] = z4;

  const int arow = w * 16 + lrow;

  for (int h = 0; h < 8; ++h) {
    const __bf16* slot = (const __bf16*)scores + (size_t)(tl * 8 + h) * 32768;
    float wh = w_head[h];

    // Q fragments straight from global [b][e] (no LDS dependency)
    bf16x8 a0 = *(const bf16x8*)(slot + arow * 64 + lk * 8);
    bf16x8 a1 = *(const bf16x8*)(slot + arow * 64 + 32 + lk * 8);

    __syncthreads();  // previous head's LDS reads done
#pragma unroll
    for (int i = 0; i < 2; ++i) {
      int cc = i * 512 + tid;
      int krow = cc >> 3, ks = cc & 7;             // K[b][e], 128B LDS rows
      uint4 kv = *(const uint4*)(slot + 8192 + krow * 64 + ks * 8);
      *(uint4*)(smem + krow * 128 + ((ks ^ (krow & 7)) << 4)) = kv;
      int e = cc >> 4, vs = cc & 15;               // V^T[e][b], 256B LDS rows
      uint4 vv = *(const uint4*)(slot + 16384 + e * 128 + vs * 8);
      *(uint4*)(smem + 16384 + e * 256 + ((vs ^ (e & 7)) << 4)) = vv;
    }
    __syncthreads();

    // S = Q K^T  (wave strip = 16 rows x 128 cols)
    f32x4 sacc[8];
#pragma unroll
    for (int ct = 0; ct < 8; ++ct) {
      int bcol = ct * 16 + lrow;
      const char* kb = smem + bcol * 128;
      int bswz = (bcol & 7) << 4;
      bf16x8 b0 = *(const bf16x8*)(kb + ((lk * 16 + 0) ^ bswz));
      bf16x8 b1 = *(const bf16x8*)(kb + ((lk * 16 + 64) ^ bswz));
      sacc[ct] = mfma16(a0, b0, z4);
      sacc[ct] = mfma16(a1, b1, sacc[ct]);
    }

    // scale * mask, emit scores
    float* srow = scores + (size_t)(tl * 8 + h) * 16384;
#pragma unroll
    for (int ct = 0; ct < 8; ++ct)
#pragma unroll
      for (int r = 0; r < 4; ++r) {
        float s = sacc[ct][r] * 0.125f * mreg[ct][r];
        sacc[ct][r] = s;
        srow[(w * 16 + lk * 4 + r) * 128 + ct * 16 + lrow] = s;
      }

    // row softmax (row lives in one 16-lane group), fold w_head, P -> LDS
#pragma unroll
    for (int r = 0; r < 4; ++r) {
      float mx = sacc[0][r];
#pragma unroll
      for (int ct = 1; ct < 8; ++ct) mx = fmaxf(mx, sacc[ct][r]);
      mx = fmaxf(mx, __shfl_xor(mx, 1));
      mx = fmaxf(mx, __shfl_xor(mx, 2));
      mx = fmaxf(mx, __shfl_xor(mx, 4));
      mx = fmaxf(mx, __shfl_xor(mx, 8));
      float sum = 0.f;
#pragma unroll
      for (int ct = 0; ct < 8; ++ct) {
        float p = __expf(sacc[ct][r] - mx);
        sacc[ct][r] = p;
        sum += p;
      }
      sum += __shfl_xor(sum, 1);
      sum += __shfl_xor(sum, 2);
      sum += __shfl_xor(sum, 4);
      sum += __shfl_xor(sum, 8);
      float fct = wh / sum;
      int row16 = lk * 4 + r;
      char* pb = smem + 32768 + w * 4096 + row16 * 256;
      int pswz = (row16 & 7) << 4;
#pragma unroll
      for (int ct = 0; ct < 8; ++ct) {
        int col = ct * 16 + lrow;
        *(__bf16*)(pb + ((col * 2) ^ pswz)) = (__bf16)(sacc[ct][r] * fct);
      }
    }

    // PV: out_acc += (wh*P) @ V   (accumulates across heads)
    const char* pab = smem + 32768 + w * 4096 + lrow * 256;
    int paswz = (lrow & 7) << 4;
    bf16x8 pa[4];
#pragma unroll
    for (int kk = 0; kk < 4; ++kk)
      pa[kk] = *(const bf16x8*)(pab + ((lk * 16 + kk * 64) ^ paswz));
#pragma unroll
    for (int ct2 = 0; ct2 < 4; ++ct2) {
      int ecol = ct2 * 16 + lrow;
      const char* vb = smem + 16384 + ecol * 256;
      int vswz = (ecol & 7) << 4;
#pragma unroll
      for (int kk = 0; kk < 4; ++kk) {
        bf16x8 b = *(const bf16x8*)(vb + ((lk * 16 + kk * 64) ^ vswz));
        oacc[ct2] = mfma16(pa[kk], b, oacc[ct2]);
      }
    }
  }

  // attn_output[b,t,l,e] : (b*512 + tl)*64 + e
#pragma unroll
  for (int ct2 = 0; ct2 < 4; ++ct2)
#pragma unroll
    for (int r = 0; r < 4; ++r) {
      int brow = w * 16 + lk * 4 + r;
      int e    = ct2 * 16 + lrow;
      out_base[(size_t)(brow * 512 + tl) * 64 + e] = oacc[ct2][r];
    }
}

extern "C" void kernel_launch(void* const* d_in, const int* in_sizes, int n_in,
                              void* d_out, int out_size, void* d_ws, size_t ws_size,
                              hipStream_t stream) {
  const float* q    = (const float*)d_in[0];
  const float* k    = (const float*)d_in[1];
  const float* v    = (const float*)d_in[2];
  const float* mask = (const float*)d_in[3];
  const float* Wq   = (const float*)d_in[4];
  const float* Wk   = (const float*)d_in[5];
  const float* Wv   = (const float*)d_in[6];
  const float* wh   = (const float*)d_in[7];
  float* out = (float*)d_out;

  __bf16* Wt  = (__bf16*)out;                  // 786 KB, inside attn region
  __bf16* qkv = (__bf16*)(out + 4194304);      // packed into scores slots

  hipLaunchKernelGGL(k0_wt,   dim3(96),      dim3(512), 0, stream, Wq, Wk, Wv, Wt);
  hipLaunchKernelGGL(k1_proj, dim3(512, 3),  dim3(512), 0, stream, q, k, v, Wt, qkv);
  hipLaunchKernelGGL(k2_attn, dim3(512),     dim3(512), 0, stream, mask, wh, out);
}

// Round 9
// 262.638 us; speedup vs baseline: 2.8879x; 1.4620x over previous
//
#include <hip/hip_runtime.h>
#include <hip/hip_bf16.h>

// Shapes: B=128, T=16, L=32, D=256, H=8, E=V=64. TL = T*L = 512.
// d_out layout (floats): [0, 4194304) attn_output (B,T,L,64)
//                        [4194304, 71303168) scores (T,L,H,128,128)
//  - K0 parks Wt (bf16, [3][512][256]) at the start of the attn region.
//  - K1 packs per-(t,l,h) slot (64 KB): Q[b=128][e=64] | K[b=128][e=64] |
//    V^T[e=64][b=128] (bf16, 48 KB used); K2 reads them then overwrites the
//    slot with fp32 scores. No d_ws usage.
//  - LESSON (R3-R8): HIP __launch_bounds__ arg2 is min BLOCKS/CU (CUDA
//    semantics), NOT waves/EU. (512,4) capped VGPR at 64 and silently
//    spilled everything. (512,2) = 16 waves/CU, VGPR cap 128.
//  - K1 R9: R2's verified acc[4][4] structure at cap 128 -> ~111 VGPR,
//    no spill, 2 blocks/CU co-resident for phase overlap.

using bf16x8 = __attribute__((ext_vector_type(8))) __bf16;
using bf16x4 = __attribute__((ext_vector_type(4))) __bf16;
using f32x4  = __attribute__((ext_vector_type(4))) float;

__device__ __forceinline__ f32x4 mfma16(bf16x8 a, bf16x8 b, f32x4 c) {
  return __builtin_amdgcn_mfma_f32_16x16x32_bf16(a, b, c, 0, 0, 0);
}

// ---------------- K0: W (256,8,64) fp32 -> Wt[mat][col=512][d=256] bf16 ----
__global__ __launch_bounds__(512) void k0_wt(const float* __restrict__ Wq,
                                             const float* __restrict__ Wk,
                                             const float* __restrict__ Wv,
                                             __bf16* __restrict__ Wt) {
  int f   = blockIdx.x * 512 + threadIdx.x;   // 96*512 = 49152 threads
  int mat = f >> 14;
  int rem = f & 16383;
  int d8  = rem >> 9;          // 0..31  (octet of d)
  int col = rem & 511;         // 0..511 (h*64+e)
  const float* W = (mat == 0) ? Wq : (mat == 1) ? Wk : Wv;
  bf16x8 v;
#pragma unroll
  for (int i = 0; i < 8; ++i) v[i] = (__bf16)W[(d8 * 8 + i) * 512 + col];
  *(bf16x8*)(Wt + mat * 131072 + col * 256 + d8 * 8) = v;
}

// ---------------- K1: projections -----------------------------------------
// block = (tl, m), 512 thr, LDS x[128][256] bf16 swz = 64 KB.
// __launch_bounds__(512, 2): 2 blocks/CU (16 waves), VGPR cap 128.
// Wave w = head. Two rh passes of acc[4][4]; kk fully unrolled; W from L2.
__global__ __launch_bounds__(512, 2) void k1_proj(const float* __restrict__ xq,
                                                  const float* __restrict__ xk,
                                                  const float* __restrict__ xv,
                                                  const __bf16* __restrict__ Wt,
                                                  __bf16* __restrict__ qkv) {
  __shared__ char smem[65536];
  const int tid  = threadIdx.x;
  const int tl   = blockIdx.x;
  const int m    = blockIdx.y;
  const int lane = tid & 63, w = tid >> 6;
  const int lrow = lane & 15, lk = lane >> 4;
  const f32x4 z4 = {0.f, 0.f, 0.f, 0.f};

  const float* xm = (m == 0) ? xq : (m == 1) ? xk : xv;

  // stage x slice [b=128][d=256] -> bf16, XOR-swizzled rows of 512 B
#pragma unroll
  for (int i = 0; i < 8; ++i) {
    int c = i * 512 + tid;
    int row = c >> 5, sl = c & 31;
    const float* g = xm + (size_t)row * 131072 + (size_t)tl * 256 + sl * 8;
    float4 f0 = *(const float4*)g;
    float4 f1 = *(const float4*)(g + 4);
    bf16x8 v;
    v[0] = (__bf16)f0.x; v[1] = (__bf16)f0.y; v[2] = (__bf16)f0.z; v[3] = (__bf16)f0.w;
    v[4] = (__bf16)f1.x; v[5] = (__bf16)f1.y; v[6] = (__bf16)f1.z; v[7] = (__bf16)f1.w;
    *(bf16x8*)(smem + row * 512 + ((sl ^ (row & 7)) << 4)) = v;
  }
  __syncthreads();

  const int h = w;                                  // wave <-> head
  const __bf16* wbase = Wt + (size_t)(m * 512 + h * 64) * 256;
  __bf16* dst = qkv + (size_t)(tl * 8 + h) * 32768 + m * 8192;

  if (m < 2) {                                      // D[e][b] = W^T x^T
#pragma unroll 1
    for (int rh = 0; rh < 2; ++rh) {                // 64 b-rows per pass
      f32x4 acc[4][4];
#pragma unroll
      for (int bi = 0; bi < 4; ++bi)
#pragma unroll
        for (int ci = 0; ci < 4; ++ci) acc[bi][ci] = z4;
#pragma unroll
      for (int kk = 0; kk < 8; ++kk) {
        bf16x8 wf[4], xf[4];
#pragma unroll
        for (int ci = 0; ci < 4; ++ci)
          wf[ci] = *(const bf16x8*)(wbase + (ci * 16 + lrow) * 256 + kk * 32 + lk * 8);
#pragma unroll
        for (int bi = 0; bi < 4; ++bi) {
          int row = rh * 64 + bi * 16 + lrow;
          xf[bi] = *(const bf16x8*)(smem + row * 512 +
                                    ((kk * 64 + lk * 16) ^ ((row & 7) << 4)));
        }
#pragma unroll
        for (int bi = 0; bi < 4; ++bi)
#pragma unroll
          for (int ci = 0; ci < 4; ++ci)
            acc[bi][ci] = mfma16(wf[ci], xf[bi], acc[bi][ci]);
      }
      // lane: e = ci*16+lk*4+r (consec), b = rh*64+bi*16+lrow -> [b][e]
#pragma unroll
      for (int bi = 0; bi < 4; ++bi)
#pragma unroll
        for (int ci = 0; ci < 4; ++ci) {
          bf16x4 v;
#pragma unroll
          for (int r = 0; r < 4; ++r) v[r] = (__bf16)acc[bi][ci][r];
          int b = rh * 64 + bi * 16 + lrow;
          *(bf16x4*)(dst + b * 64 + ci * 16 + lk * 4) = v;
        }
    }
  } else {                                          // D[b][e] = x W
#pragma unroll 1
    for (int rh = 0; rh < 2; ++rh) {
      f32x4 acc[4][4];
#pragma unroll
      for (int bi = 0; bi < 4; ++bi)
#pragma unroll
        for (int ci = 0; ci < 4; ++ci) acc[bi][ci] = z4;
#pragma unroll
      for (int kk = 0; kk < 8; ++kk) {
        bf16x8 wf[4], xf[4];
#pragma unroll
        for (int ci = 0; ci < 4; ++ci)
          wf[ci] = *(const bf16x8*)(wbase + (ci * 16 + lrow) * 256 + kk * 32 + lk * 8);
#pragma unroll
        for (int bi = 0; bi < 4; ++bi) {
          int row = rh * 64 + bi * 16 + lrow;
          xf[bi] = *(const bf16x8*)(smem + row * 512 +
                                    ((kk * 64 + lk * 16) ^ ((row & 7) << 4)));
        }
#pragma unroll
        for (int bi = 0; bi < 4; ++bi)
#pragma unroll
          for (int ci = 0; ci < 4; ++ci)
            acc[bi][ci] = mfma16(xf[bi], wf[ci], acc[bi][ci]);
      }
      // lane: b = rh*64+bi*16+lk*4+r (consec), e = ci*16+lrow -> V^T [e][b]
#pragma unroll
      for (int bi = 0; bi < 4; ++bi)
#pragma unroll
        for (int ci = 0; ci < 4; ++ci) {
          bf16x4 v;
#pragma unroll
          for (int r = 0; r < 4; ++r) v[r] = (__bf16)acc[bi][ci][r];
          int e = ci * 16 + lrow;
          *(bf16x4*)(dst + e * 128 + rh * 64 + bi * 16 + lk * 4) = v;
        }
    }
  }
}

// ---------------- K2: scores + softmax + PV + head mix --------------------
// block = (t,l), loops h. LDS: K 16K @0 | V^T 16K @16384 | P 32K @32768
__global__ __launch_bounds__(512) void k2_attn(const float* __restrict__ mask,
                                               const float* __restrict__ w_head,
                                               float* out_base) {
  __shared__ char smem[65536];
  const int tid  = threadIdx.x;
  const int tl   = blockIdx.x;
  const int lane = tid & 63, w = tid >> 6;
  const int lrow = lane & 15, lk = lane >> 4;
  const f32x4 z4 = {0.f, 0.f, 0.f, 0.f};

  float* scores = out_base + 4194304;

  // per-lane mask values (reused for all 8 heads)
  float mreg[8][4];
#pragma unroll
  for (int ct = 0; ct < 8; ++ct)
#pragma unroll
    for (int r = 0; r < 4; ++r)
      mreg[ct][r] = mask[(w * 16 + lk * 4 + r) * 128 + ct * 16 + lrow];

  f32x4 oacc[4];
#pragma unroll
  for (int i = 0; i < 4; ++i) oacc[i] = z4;

  const int arow = w * 16 + lrow;

  for (int h = 0; h < 8; ++h) {
    const __bf16* slot = (const __bf16*)scores + (size_t)(tl * 8 + h) * 32768;
    float wh = w_head[h];

    // Q fragments straight from global [b][e] (no LDS dependency)
    bf16x8 a0 = *(const bf16x8*)(slot + arow * 64 + lk * 8);
    bf16x8 a1 = *(const bf16x8*)(slot + arow * 64 + 32 + lk * 8);

    __syncthreads();  // previous head's LDS reads done
#pragma unroll
    for (int i = 0; i < 2; ++i) {
      int cc = i * 512 + tid;
      int krow = cc >> 3, ks = cc & 7;             // K[b][e], 128B LDS rows
      uint4 kv = *(const uint4*)(slot + 8192 + krow * 64 + ks * 8);
      *(uint4*)(smem + krow * 128 + ((ks ^ (krow & 7)) << 4)) = kv;
      int e = cc >> 4, vs = cc & 15;               // V^T[e][b], 256B LDS rows
      uint4 vv = *(const uint4*)(slot + 16384 + e * 128 + vs * 8);
      *(uint4*)(smem + 16384 + e * 256 + ((vs ^ (e & 7)) << 4)) = vv;
    }
    __syncthreads();

    // S = Q K^T  (wave strip = 16 rows x 128 cols)
    f32x4 sacc[8];
#pragma unroll
    for (int ct = 0; ct < 8; ++ct) {
      int bcol = ct * 16 + lrow;
      const char* kb = smem + bcol * 128;
      int bswz = (bcol & 7) << 4;
      bf16x8 b0 = *(const bf16x8*)(kb + ((lk * 16 + 0) ^ bswz));
      bf16x8 b1 = *(const bf16x8*)(kb + ((lk * 16 + 64) ^ bswz));
      sacc[ct] = mfma16(a0, b0, z4);
      sacc[ct] = mfma16(a1, b1, sacc[ct]);
    }

    // scale * mask, emit scores
    float* srow = scores + (size_t)(tl * 8 + h) * 16384;
#pragma unroll
    for (int ct = 0; ct < 8; ++ct)
#pragma unroll
      for (int r = 0; r < 4; ++r) {
        float s = sacc[ct][r] * 0.125f * mreg[ct][r];
        sacc[ct][r] = s;
        srow[(w * 16 + lk * 4 + r) * 128 + ct * 16 + lrow] = s;
      }

    // row softmax (row lives in one 16-lane group), fold w_head, P -> LDS
#pragma unroll
    for (int r = 0; r < 4; ++r) {
      float mx = sacc[0][r];
#pragma unroll
      for (int ct = 1; ct < 8; ++ct) mx = fmaxf(mx, sacc[ct][r]);
      mx = fmaxf(mx, __shfl_xor(mx, 1));
      mx = fmaxf(mx, __shfl_xor(mx, 2));
      mx = fmaxf(mx, __shfl_xor(mx, 4));
      mx = fmaxf(mx, __shfl_xor(mx, 8));
      float sum = 0.f;
#pragma unroll
      for (int ct = 0; ct < 8; ++ct) {
        float p = __expf(sacc[ct][r] - mx);
        sacc[ct][r] = p;
        sum += p;
      }
      sum += __shfl_xor(sum, 1);
      sum += __shfl_xor(sum, 2);
      sum += __shfl_xor(sum, 4);
      sum += __shfl_xor(sum, 8);
      float fct = wh / sum;
      int row16 = lk * 4 + r;
      char* pb = smem + 32768 + w * 4096 + row16 * 256;
      int pswz = (row16 & 7) << 4;
#pragma unroll
      for (int ct = 0; ct < 8; ++ct) {
        int col = ct * 16 + lrow;
        *(__bf16*)(pb + ((col * 2) ^ pswz)) = (__bf16)(sacc[ct][r] * fct);
      }
    }

    // PV: out_acc += (wh*P) @ V   (accumulates across heads)
    const char* pab = smem + 32768 + w * 4096 + lrow * 256;
    int paswz = (lrow & 7) << 4;
    bf16x8 pa[4];
#pragma unroll
    for (int kk = 0; kk < 4; ++kk)
      pa[kk] = *(const bf16x8*)(pab + ((lk * 16 + kk * 64) ^ paswz));
#pragma unroll
    for (int ct2 = 0; ct2 < 4; ++ct2) {
      int ecol = ct2 * 16 + lrow;
      const char* vb = smem + 16384 + ecol * 256;
      int vswz = (ecol & 7) << 4;
#pragma unroll
      for (int kk = 0; kk < 4; ++kk) {
        bf16x8 b = *(const bf16x8*)(vb + ((lk * 16 + kk * 64) ^ vswz));
        oacc[ct2] = mfma16(pa[kk], b, oacc[ct2]);
      }
    }
  }

  // attn_output[b,t,l,e] : (b*512 + tl)*64 + e
#pragma unroll
  for (int ct2 = 0; ct2 < 4; ++ct2)
#pragma unroll
    for (int r = 0; r < 4; ++r) {
      int brow = w * 16 + lk * 4 + r;
      int e    = ct2 * 16 + lrow;
      out_base[(size_t)(brow * 512 + tl) * 64 + e] = oacc[ct2][r];
    }
}

extern "C" void kernel_launch(void* const* d_in, const int* in_sizes, int n_in,
                              void* d_out, int out_size, void* d_ws, size_t ws_size,
                              hipStream_t stream) {
  const float* q    = (const float*)d_in[0];
  const float* k    = (const float*)d_in[1];
  const float* v    = (const float*)d_in[2];
  const float* mask = (const float*)d_in[3];
  const float* Wq   = (const float*)d_in[4];
  const float* Wk   = (const float*)d_in[5];
  const float* Wv   = (const float*)d_in[6];
  const float* wh   = (const float*)d_in[7];
  float* out = (float*)d_out;

  __bf16* Wt  = (__bf16*)out;                  // 786 KB, inside attn region
  __bf16* qkv = (__bf16*)(out + 4194304);      // packed into scores slots

  hipLaunchKernelGGL(k0_wt,   dim3(96),      dim3(512), 0, stream, Wq, Wk, Wv, Wt);
  hipLaunchKernelGGL(k1_proj, dim3(512, 3),  dim3(512), 0, stream, q, k, v, Wt, qkv);
  hipLaunchKernelGGL(k2_attn, dim3(512),     dim3(512), 0, stream, mask, wh, out);
}